// Round 16
// baseline (230.994 us; speedup 1.0000x reference)
//
#include <hip/hip_runtime.h>

#define N_PTS 32768
#define M_Q   8192
#define C_F   256
#define GS    32
#define NC    (GS * GS * GS)          // 32768 cells per side
#define TOTP  (2 * N_PTS)             // 65536 points
#define TOTQ  (2 * M_Q)               // 16384 queries
#define LOC   (-4.4f)
#define CWID  (8.8f / GS)             // 0.275
#define INVW  (GS / 8.8f)
#define MARG  2e-4f
#define INF_F __int_as_float(0x7f800000)
#define MAXI  0x7fffffff

__device__ __forceinline__ float rn_mul(float a, float b) { return __fmul_rn(a, b); }
__device__ __forceinline__ float rn_add(float a, float b) { return __fadd_rn(a, b); }

__device__ __forceinline__ int cellco(float v) {
    int c = (int)floorf((v - LOC) * INVW);
    return c < 0 ? 0 : (c > GS - 1 ? GS - 1 : c);
}

// exact lexicographic (d,i) insert into running top-2 pair
__device__ __forceinline__ void ins_lex(float d, int i, float& b1, int& j1,
                                        float& b2, int& j2) {
    bool lt1 = (d < b1) || (d == b1 && i < j1);
    bool lt2 = (d < b2) || (d == b2 && i < j2);
    b2 = lt1 ? b1 : (lt2 ? d : b2);
    j2 = lt1 ? j1 : (lt2 ? i : j2);
    b1 = lt1 ? d : b1;
    j1 = lt1 ? i : j1;
}
__device__ __forceinline__ void ins_lex2(float d, int i, float& b2, int& j2) {
    bool lt2 = (d < b2) || (d == b2 && i < j2);
    b2 = lt2 ? d : b2;
    j2 = lt2 ? i : j2;
}

// merge two sorted value-pairs -> two smallest values (multiset-exact)
__device__ __forceinline__ void vpair_merge(float& a1, float& a2, float b1, float b2) {
    float n1 = fminf(a1, b1);
    float n2 = fminf(fmaxf(a1, b1), fminf(a2, b2));
    a1 = n1; a2 = n2;
}

// K1: per-point cell id + histogram
__global__ __launch_bounds__(256) void build_cells(
    const float* __restrict__ c0, const float* __restrict__ c1,
    int* __restrict__ counts, int* __restrict__ cid)
{
    int t = blockIdx.x * 256 + threadIdx.x;     // 0..65535
    int side = t >> 15, n = t & (N_PTS - 1);
    const float* c = side ? c1 : c0;
    float x = c[n * 3], y = c[n * 3 + 1], z = c[n * 3 + 2];
    int g = side * NC + (cellco(z) * GS + cellco(y)) * GS + cellco(x);
    cid[t] = g;
    atomicAdd(&counts[g], 1);
}

// K2: per-256-block exclusive scan, emit block sums
__global__ __launch_bounds__(256) void scan1(const int* __restrict__ counts,
                                             int* __restrict__ starts,
                                             int* __restrict__ bsum)
{
    __shared__ int s[256];
    int b = blockIdx.x, tid = threadIdx.x;
    int v = counts[b * 256 + tid];
    s[tid] = v;
    __syncthreads();
    for (int o = 1; o < 256; o <<= 1) {
        int u = (tid >= o) ? s[tid - o] : 0;
        __syncthreads();
        s[tid] += u;
        __syncthreads();
    }
    starts[b * 256 + tid] = s[tid] - v;   // exclusive
    if (tid == 255) bsum[b] = s[255];
}

// K3: exclusive scan of the 256 block sums (single block)
__global__ __launch_bounds__(256) void scan2(int* __restrict__ bsum) {
    __shared__ int s[256];
    int tid = threadIdx.x;
    int v = bsum[tid];
    s[tid] = v;
    __syncthreads();
    for (int o = 1; o < 256; o <<= 1) {
        int u = (tid >= o) ? s[tid - o] : 0;
        __syncthreads();
        s[tid] += u;
        __syncthreads();
    }
    bsum[tid] = s[tid] - v;
}

// K4: add block offsets + sentinel
__global__ __launch_bounds__(256) void scan3(int* __restrict__ starts,
                                             const int* __restrict__ bsum)
{
    int b = blockIdx.x, tid = threadIdx.x;
    starts[b * 256 + tid] += bsum[b];
    if (b == 0 && tid == 0) starts[TOTP] = TOTP;   // sentinel
}

// K5: scatter points into cell-sorted pool
__global__ __launch_bounds__(256) void scatter(
    const float* __restrict__ c0, const float* __restrict__ c1,
    const int* __restrict__ cid, const int* __restrict__ starts,
    int* __restrict__ counts, float4* __restrict__ pts4, int* __restrict__ pidx)
{
    int t = blockIdx.x * 256 + threadIdx.x;
    int side = t >> 15, n = t & (N_PTS - 1);
    const float* c = side ? c1 : c0;
    float x = c[n * 3], y = c[n * 3 + 1], z = c[n * 3 + 2];
    float b2 = rn_add(rn_add(rn_mul(x, x), rn_mul(y, y)), rn_mul(z, z));
    int g = cid[t];
    int pos = starts[g] + (atomicSub(&counts[g], 1) - 1);
    pts4[pos] = make_float4(x, y, z, b2);
    pidx[pos] = n;
}

// K6: one WAVE per query (4 independent waves per 256-thread block).
// Step 1: full r<=2 cube (125 cells, lane-parallel). Cheap value-exact stop.
// Tail shells {3,5,8,13,21,31} with Chebyshev skip. One exact lex butterfly.
__global__ __launch_bounds__(256) void query2nn(
    const float* __restrict__ src, const float* __restrict__ tgt,
    const float* __restrict__ sc0, const float* __restrict__ sc1,
    const float4* __restrict__ pts4, const int* __restrict__ pidx,
    const int* __restrict__ starts, float* __restrict__ out)
{
    int lane = threadIdx.x & 63;
    int wv   = threadIdx.x >> 6;
    int qid  = blockIdx.x * 4 + wv;          // 0..16383
    int side = qid >> 13, q = qid & (M_Q - 1);
    const float* sc = side ? sc1 : sc0;

    float ax = sc[q * 3], ay = sc[q * 3 + 1], az = sc[q * 3 + 2];
    float a2 = rn_add(rn_add(rn_mul(ax, ax), rn_mul(ay, ay)), rn_mul(az, az));
    int cx = cellco(ax), cy = cellco(ay), cz = cellco(az);
    const int* st = starts + side * NC;

    float d1 = INF_F, d2 = INF_F;            // per-lane privates (disjoint cells)
    int   i1 = MAXI,  i2 = MAXI;

    auto scan_cell = [&](int xx, int yy, int zz) {
        int c = (zz * GS + yy) * GS + xx;
        int s0 = st[c], s1 = st[c + 1];
        for (int j = s0; j < s1; ++j) {
            float4 p = pts4[j];
            float dot = __builtin_fmaf(az, p.z,
                         __builtin_fmaf(ay, p.y, rn_mul(ax, p.x)));
            float dd = __builtin_fmaf(-2.0f, dot, rn_add(a2, p.w));
            ins_lex(dd, pidx[j], d1, i1, d2, i2);
        }
    };

    auto stop_bnd = [&](int r) {
        float bnd = INF_F;
        if (cx - r > 0)      bnd = fminf(bnd, ax - (LOC + (cx - r) * CWID));
        if (cx + r < GS - 1) bnd = fminf(bnd, (LOC + (cx + r + 1) * CWID) - ax);
        if (cy - r > 0)      bnd = fminf(bnd, ay - (LOC + (cy - r) * CWID));
        if (cy + r < GS - 1) bnd = fminf(bnd, (LOC + (cy + r + 1) * CWID) - ay);
        if (cz - r > 0)      bnd = fminf(bnd, az - (LOC + (cz - r) * CWID));
        if (cz + r < GS - 1) bnd = fminf(bnd, (LOC + (cz + r + 1) * CWID) - az);
        return bnd;
    };

    auto cheap_t2 = [&]() {                  // exact global 2nd-smallest VALUE
        float p1 = d1, p2 = d2;
#pragma unroll
        for (int mk = 1; mk < 64; mk <<= 1) {
            float o1 = __shfl_xor(p1, mk);
            float o2 = __shfl_xor(p2, mk);
            vpair_merge(p1, p2, o1, o2);
        }
        return p2;
    };

    // ---- Step 1: full r<=2 cube: 125 cells, lane-strided ----
#pragma unroll
    for (int k0 = 0; k0 < 2; ++k0) {
        int k = k0 * 64 + lane;
        if (k < 125) {
            int dz = k / 25, rem = k - dz * 25;
            int dy = rem / 5, dx = rem - dy * 5;
            int xx = cx + dx - 2, yy = cy + dy - 2, zz = cz + dz - 2;
            if ((unsigned)xx < GS && (unsigned)yy < GS && (unsigned)zz < GS)
                scan_cell(xx, yy, zz);
        }
    }
    int rprev = 2;
    {
        float bnd = stop_bnd(2);
        float t2v = cheap_t2();
        if (!(bnd == INF_F || t2v < bnd * bnd - MARG)) {
            // ---- tail shells for sparse-region queries ----
            const int rs[6] = {3, 5, 8, 13, 21, 31};
#pragma unroll 1
            for (int si = 0; si < 6; ++si) {
                int r = rs[si];
                int S = 2 * r + 1, S2 = S * S, tot = S * S2;
                for (int k = lane; k < tot; k += 64) {
                    int dz = k / S2;
                    int rem = k - dz * S2;
                    int dy = rem / S;
                    int dx = rem - dy * S;
                    dx -= r; dy -= r; dz -= r;
                    int adx = dx < 0 ? -dx : dx;
                    int ady = dy < 0 ? -dy : dy;
                    int adz = dz < 0 ? -dz : dz;
                    int ch = max(adx, max(ady, adz));
                    if (ch <= rprev) continue;                 // already scanned
                    int xx = cx + dx, yy = cy + dy, zz = cz + dz;
                    if ((unsigned)xx >= GS || (unsigned)yy >= GS ||
                        (unsigned)zz >= GS) continue;
                    scan_cell(xx, yy, zz);
                }
                rprev = r;
                bnd = stop_bnd(r);
                t2v = cheap_t2();
                if (bnd == INF_F || t2v < bnd * bnd - MARG) break;
            }
        }
    }

    // ---- one exact lex butterfly (privates are pure; disjoint cell sets) ----
    float t1 = d1, t2 = d2; int u1 = i1, u2 = i2;
#pragma unroll
    for (int mk = 1; mk < 64; mk <<= 1) {
        float o1 = __shfl_xor(t1, mk); int p1 = __shfl_xor(u1, mk);
        float o2 = __shfl_xor(t2, mk); int p2 = __shfl_xor(u2, mk);
        ins_lex(o1, p1, t1, u1, t2, u2);
        ins_lex2(o2, p2, t2, u2);
    }

    // fused gather: result uniform across the wave; 64 lanes x float4 = row
    const float* feats = side ? tgt : src;
    const float4* sp = (const float4*)(feats + (size_t)u2 * C_F);
    float4* dp = (float4*)(out + (size_t)qid * C_F);
    dp[lane] = sp[lane];
}

extern "C" void kernel_launch(void* const* d_in, const int* in_sizes, int n_in,
                              void* d_out, int out_size, void* d_ws, size_t ws_size,
                              hipStream_t stream) {
    const float* src  = (const float*)d_in[0];
    const float* tgt  = (const float*)d_in[1];
    const float* c0   = (const float*)d_in[2];  // src_coords   (N,3)
    const float* c1   = (const float*)d_in[3];  // tgt_coords   (N,3)
    const float* sh0  = (const float*)d_in[4];  // src_shortcut (M,3)
    const float* sh1  = (const float*)d_in[5];  // tgt_shortcut (M,3)
    float* out = (float*)d_out;

    char* w = (char*)d_ws;
    float4* pts4   = (float4*)(w);                       // 1,048,576
    int*    pidx   = (int*)(w + 1048576);                //   262,144
    int*    cid    = (int*)(w + 1310720);                //   262,144
    int*    counts = (int*)(w + 1572864);                //   262,144
    int*    starts = (int*)(w + 1835008);                //   262,148 (65537)
    int*    bsum   = (int*)(w + 2097280);                //     1,024

    hipMemsetAsync(counts, 0, (size_t)TOTP * sizeof(int), stream);

    hipLaunchKernelGGL(build_cells, dim3(TOTP / 256), dim3(256), 0, stream,
                       c0, c1, counts, cid);
    hipLaunchKernelGGL(scan1, dim3(TOTP / 256), dim3(256), 0, stream,
                       counts, starts, bsum);
    hipLaunchKernelGGL(scan2, dim3(1), dim3(256), 0, stream, bsum);
    hipLaunchKernelGGL(scan3, dim3(TOTP / 256), dim3(256), 0, stream,
                       starts, bsum);
    hipLaunchKernelGGL(scatter, dim3(TOTP / 256), dim3(256), 0, stream,
                       c0, c1, cid, starts, counts, pts4, pidx);
    hipLaunchKernelGGL(query2nn, dim3(TOTQ / 4), dim3(256), 0, stream,
                       src, tgt, sh0, sh1, pts4, pidx, starts, out);
}

// Round 17
// 136.587 us; speedup vs baseline: 1.6912x; 1.6912x over previous
//
#include <hip/hip_runtime.h>

#define N_PTS 32768
#define M_Q   8192
#define C_F   256
#define GS    32
#define NC    (GS * GS * GS)          // 32768 cells per side
#define TOTP  (2 * N_PTS)             // 65536 points
#define TOTQ  (2 * M_Q)               // 16384 queries
#define LOC   (-4.4f)
#define CWID  (8.8f / GS)             // 0.275
#define INVW  (GS / 8.8f)
#define MARG  2e-4f
#define INF_F __int_as_float(0x7f800000)
#define MAXI  0x7fffffff

__device__ __forceinline__ float rn_mul(float a, float b) { return __fmul_rn(a, b); }
__device__ __forceinline__ float rn_add(float a, float b) { return __fadd_rn(a, b); }

__device__ __forceinline__ int cellco(float v) {
    int c = (int)floorf((v - LOC) * INVW);
    return c < 0 ? 0 : (c > GS - 1 ? GS - 1 : c);
}

// exact lexicographic (d,i) insert into running top-2 pair
__device__ __forceinline__ void ins_lex(float d, int i, float& b1, int& j1,
                                        float& b2, int& j2) {
    bool lt1 = (d < b1) || (d == b1 && i < j1);
    bool lt2 = (d < b2) || (d == b2 && i < j2);
    b2 = lt1 ? b1 : (lt2 ? d : b2);
    j2 = lt1 ? j1 : (lt2 ? i : j2);
    b1 = lt1 ? d : b1;
    j1 = lt1 ? i : j1;
}
__device__ __forceinline__ void ins_lex2(float d, int i, float& b2, int& j2) {
    bool lt2 = (d < b2) || (d == b2 && i < j2);
    b2 = lt2 ? d : b2;
    j2 = lt2 ? i : j2;
}

// merge two sorted value-pairs -> two smallest values (multiset-exact)
__device__ __forceinline__ void vpair_merge(float& a1, float& a2, float b1, float b2) {
    float n1 = fminf(a1, b1);
    float n2 = fminf(fmaxf(a1, b1), fminf(a2, b2));
    a1 = n1; a2 = n2;
}

// K1: per-point cell id + histogram
__global__ __launch_bounds__(256) void build_cells(
    const float* __restrict__ c0, const float* __restrict__ c1,
    int* __restrict__ counts, int* __restrict__ cid)
{
    int t = blockIdx.x * 256 + threadIdx.x;     // 0..65535
    int side = t >> 15, n = t & (N_PTS - 1);
    const float* c = side ? c1 : c0;
    float x = c[n * 3], y = c[n * 3 + 1], z = c[n * 3 + 2];
    int g = side * NC + (cellco(z) * GS + cellco(y)) * GS + cellco(x);
    cid[t] = g;
    atomicAdd(&counts[g], 1);
}

// K2: per-256-block exclusive scan, emit block sums
__global__ __launch_bounds__(256) void scan1(const int* __restrict__ counts,
                                             int* __restrict__ starts,
                                             int* __restrict__ bsum)
{
    __shared__ int s[256];
    int b = blockIdx.x, tid = threadIdx.x;
    int v = counts[b * 256 + tid];
    s[tid] = v;
    __syncthreads();
    for (int o = 1; o < 256; o <<= 1) {
        int u = (tid >= o) ? s[tid - o] : 0;
        __syncthreads();
        s[tid] += u;
        __syncthreads();
    }
    starts[b * 256 + tid] = s[tid] - v;   // exclusive
    if (tid == 255) bsum[b] = s[255];
}

// K3: exclusive scan of the 256 block sums (single block)
__global__ __launch_bounds__(256) void scan2(int* __restrict__ bsum) {
    __shared__ int s[256];
    int tid = threadIdx.x;
    int v = bsum[tid];
    s[tid] = v;
    __syncthreads();
    for (int o = 1; o < 256; o <<= 1) {
        int u = (tid >= o) ? s[tid - o] : 0;
        __syncthreads();
        s[tid] += u;
        __syncthreads();
    }
    bsum[tid] = s[tid] - v;
}

// K4: add block offsets + sentinel
__global__ __launch_bounds__(256) void scan3(int* __restrict__ starts,
                                             const int* __restrict__ bsum)
{
    int b = blockIdx.x, tid = threadIdx.x;
    starts[b * 256 + tid] += bsum[b];
    if (b == 0 && tid == 0) starts[TOTP] = TOTP;   // sentinel
}

// K5: scatter points into cell-sorted pool
__global__ __launch_bounds__(256) void scatter(
    const float* __restrict__ c0, const float* __restrict__ c1,
    const int* __restrict__ cid, const int* __restrict__ starts,
    int* __restrict__ counts, float4* __restrict__ pts4, int* __restrict__ pidx)
{
    int t = blockIdx.x * 256 + threadIdx.x;
    int side = t >> 15, n = t & (N_PTS - 1);
    const float* c = side ? c1 : c0;
    float x = c[n * 3], y = c[n * 3 + 1], z = c[n * 3 + 2];
    float b2 = rn_add(rn_add(rn_mul(x, x), rn_mul(y, y)), rn_mul(z, z));
    int g = cid[t];
    int pos = starts[g] + (atomicSub(&counts[g], 1) - 1);
    pts4[pos] = make_float4(x, y, z, b2);
    pidx[pos] = n;
}

// K6: one WAVE per query (4 independent waves / 256-thread block).
// Cells of a (dz,dy) row are x-contiguous in the sorted array -> each row is
// ONE contiguous point range scanned lane-strided (coalesced, all 64 lanes).
// Ring expansion splits previously-scanned rows into 2 unscanned sub-ranges
// (exactly-once insertion). Value-only stop per radius; one lex butterfly.
__global__ __launch_bounds__(256) void query2nn(
    const float* __restrict__ src, const float* __restrict__ tgt,
    const float* __restrict__ sc0, const float* __restrict__ sc1,
    const float4* __restrict__ pts4, const int* __restrict__ pidx,
    const int* __restrict__ starts, float* __restrict__ out)
{
    int lane = threadIdx.x & 63;
    int wv   = threadIdx.x >> 6;
    int qid  = blockIdx.x * 4 + wv;          // 0..16383
    int side = qid >> 13, q = qid & (M_Q - 1);
    const float* sc = side ? sc1 : sc0;

    float ax = sc[q * 3], ay = sc[q * 3 + 1], az = sc[q * 3 + 2];
    float a2 = rn_add(rn_add(rn_mul(ax, ax), rn_mul(ay, ay)), rn_mul(az, az));
    int cx = cellco(ax), cy = cellco(ay), cz = cellco(az);
    const int* st = starts + side * NC;

    float d1 = INF_F, d2 = INF_F;            // per-lane privates (disjoint pts)
    int   i1 = MAXI,  i2 = MAXI;

    // scan contiguous x-range [x0,x1] of row (zz,yy), lane-strided
    auto scan_range = [&](int rowbase, int x0, int x1) {
        if (x1 < x0) return;
        int s0 = st[rowbase + x0], s1 = st[rowbase + x1 + 1];
        for (int j = s0 + lane; j < s1; j += 64) {
            float4 p = pts4[j];
            float dot = __builtin_fmaf(az, p.z,
                         __builtin_fmaf(ay, p.y, rn_mul(ax, p.x)));
            float dd = __builtin_fmaf(-2.0f, dot, rn_add(a2, p.w));
            ins_lex(dd, pidx[j], d1, i1, d2, i2);
        }
    };

    int rprev = -1;
    const int rs[8] = {1, 2, 3, 5, 8, 13, 21, 31};
#pragma unroll 1
    for (int si = 0; si < 8; ++si) {
        int r = rs[si];
        int xlo = max(cx - r, 0), xhi = min(cx + r, GS - 1);
#pragma unroll 1
        for (int dz = -r; dz <= r; ++dz) {
            int zz = cz + dz;
            if ((unsigned)zz >= GS) continue;
            int adz = dz < 0 ? -dz : dz;
#pragma unroll 1
            for (int dy = -r; dy <= r; ++dy) {
                int yy = cy + dy;
                if ((unsigned)yy >= GS) continue;
                int ady = dy < 0 ? -dy : dy;
                int rowbase = (zz * GS + yy) * GS;
                if (max(adz, ady) <= rprev) {
                    // inner x-range [cx-rprev, cx+rprev] already scanned
                    scan_range(rowbase, xlo, min(cx - rprev - 1, xhi));
                    scan_range(rowbase, max(cx + rprev + 1, xlo), xhi);
                } else {
                    scan_range(rowbase, xlo, xhi);
                }
            }
        }
        rprev = r;

        // stop bound: min distance to active faces of the scanned cube
        float bnd = INF_F;
        if (cx - r > 0)      bnd = fminf(bnd, ax - (LOC + (cx - r) * CWID));
        if (cx + r < GS - 1) bnd = fminf(bnd, (LOC + (cx + r + 1) * CWID) - ax);
        if (cy - r > 0)      bnd = fminf(bnd, ay - (LOC + (cy - r) * CWID));
        if (cy + r < GS - 1) bnd = fminf(bnd, (LOC + (cy + r + 1) * CWID) - ay);
        if (cz - r > 0)      bnd = fminf(bnd, az - (LOC + (cz - r) * CWID));
        if (cz + r < GS - 1) bnd = fminf(bnd, (LOC + (cz + r + 1) * CWID) - az);
        if (bnd == INF_F) break;                 // entire grid examined

        // cheap exact 2nd-smallest VALUE across lanes for the stop test
        float p1 = d1, p2 = d2;
#pragma unroll
        for (int mk = 1; mk < 64; mk <<= 1) {
            float o1 = __shfl_xor(p1, mk);
            float o2 = __shfl_xor(p2, mk);
            vpair_merge(p1, p2, o1, o2);
        }
        if (p2 < bnd * bnd - MARG) break;        // rigorous exact stop
    }

    // ---- one exact lex butterfly (privates pure; disjoint point sets) ----
    float t1 = d1, t2 = d2; int u1 = i1, u2 = i2;
#pragma unroll
    for (int mk = 1; mk < 64; mk <<= 1) {
        float o1 = __shfl_xor(t1, mk); int p1 = __shfl_xor(u1, mk);
        float o2 = __shfl_xor(t2, mk); int p2 = __shfl_xor(u2, mk);
        ins_lex(o1, p1, t1, u1, t2, u2);
        ins_lex2(o2, p2, t2, u2);
    }

    // fused gather: result uniform across the wave; 64 lanes x float4 = row
    const float* feats = side ? tgt : src;
    const float4* sp = (const float4*)(feats + (size_t)u2 * C_F);
    float4* dp = (float4*)(out + (size_t)qid * C_F);
    dp[lane] = sp[lane];
}

extern "C" void kernel_launch(void* const* d_in, const int* in_sizes, int n_in,
                              void* d_out, int out_size, void* d_ws, size_t ws_size,
                              hipStream_t stream) {
    const float* src  = (const float*)d_in[0];
    const float* tgt  = (const float*)d_in[1];
    const float* c0   = (const float*)d_in[2];  // src_coords   (N,3)
    const float* c1   = (const float*)d_in[3];  // tgt_coords   (N,3)
    const float* sh0  = (const float*)d_in[4];  // src_shortcut (M,3)
    const float* sh1  = (const float*)d_in[5];  // tgt_shortcut (M,3)
    float* out = (float*)d_out;

    char* w = (char*)d_ws;
    float4* pts4   = (float4*)(w);                       // 1,048,576
    int*    pidx   = (int*)(w + 1048576);                //   262,144
    int*    cid    = (int*)(w + 1310720);                //   262,144
    int*    counts = (int*)(w + 1572864);                //   262,144
    int*    starts = (int*)(w + 1835008);                //   262,148 (65537)
    int*    bsum   = (int*)(w + 2097280);                //     1,024

    hipMemsetAsync(counts, 0, (size_t)TOTP * sizeof(int), stream);

    hipLaunchKernelGGL(build_cells, dim3(TOTP / 256), dim3(256), 0, stream,
                       c0, c1, counts, cid);
    hipLaunchKernelGGL(scan1, dim3(TOTP / 256), dim3(256), 0, stream,
                       counts, starts, bsum);
    hipLaunchKernelGGL(scan2, dim3(1), dim3(256), 0, stream, bsum);
    hipLaunchKernelGGL(scan3, dim3(TOTP / 256), dim3(256), 0, stream,
                       starts, bsum);
    hipLaunchKernelGGL(scatter, dim3(TOTP / 256), dim3(256), 0, stream,
                       c0, c1, cid, starts, counts, pts4, pidx);
    hipLaunchKernelGGL(query2nn, dim3(TOTQ / 4), dim3(256), 0, stream,
                       src, tgt, sh0, sh1, pts4, pidx, starts, out);
}

// Round 18
// 89.436 us; speedup vs baseline: 2.5828x; 1.5272x over previous
//
#include <hip/hip_runtime.h>

#define N_PTS 32768
#define M_Q   8192
#define C_F   256
#define GS    32
#define NC    (GS * GS * GS)          // 32768 cells per side
#define TOTP  (2 * N_PTS)             // 65536 points
#define TOTQ  (2 * M_Q)               // 16384 queries
#define LOC   (-4.4f)
#define CWID  (8.8f / GS)             // 0.275
#define INVW  (GS / 8.8f)
#define MARG  2e-4f
#define INF_F __int_as_float(0x7f800000)
#define MAXI  0x7fffffff

__device__ __forceinline__ float rn_mul(float a, float b) { return __fmul_rn(a, b); }
__device__ __forceinline__ float rn_add(float a, float b) { return __fadd_rn(a, b); }

__device__ __forceinline__ int cellco(float v) {
    int c = (int)floorf((v - LOC) * INVW);
    return c < 0 ? 0 : (c > GS - 1 ? GS - 1 : c);
}

// exact lexicographic (d,i) insert into running top-2 pair
__device__ __forceinline__ void ins_lex(float d, int i, float& b1, int& j1,
                                        float& b2, int& j2) {
    bool lt1 = (d < b1) || (d == b1 && i < j1);
    bool lt2 = (d < b2) || (d == b2 && i < j2);
    b2 = lt1 ? b1 : (lt2 ? d : b2);
    j2 = lt1 ? j1 : (lt2 ? i : j2);
    b1 = lt1 ? d : b1;
    j1 = lt1 ? i : j1;
}
__device__ __forceinline__ void ins_lex2(float d, int i, float& b2, int& j2) {
    bool lt2 = (d < b2) || (d == b2 && i < j2);
    b2 = lt2 ? d : b2;
    j2 = lt2 ? i : j2;
}

// merge two sorted value-pairs -> two smallest values (multiset-exact)
__device__ __forceinline__ void vpair_merge(float& a1, float& a2, float b1, float b2) {
    float n1 = fminf(a1, b1);
    float n2 = fminf(fmaxf(a1, b1), fminf(a2, b2));
    a1 = n1; a2 = n2;
}

// K1: per-point cell id + histogram
__global__ __launch_bounds__(256) void build_cells(
    const float* __restrict__ c0, const float* __restrict__ c1,
    int* __restrict__ counts, int* __restrict__ cid)
{
    int t = blockIdx.x * 256 + threadIdx.x;     // 0..65535
    int side = t >> 15, n = t & (N_PTS - 1);
    const float* c = side ? c1 : c0;
    float x = c[n * 3], y = c[n * 3 + 1], z = c[n * 3 + 2];
    int g = side * NC + (cellco(z) * GS + cellco(y)) * GS + cellco(x);
    cid[t] = g;
    atomicAdd(&counts[g], 1);
}

// K2: per-256-block exclusive scan, emit block sums
__global__ __launch_bounds__(256) void scan1(const int* __restrict__ counts,
                                             int* __restrict__ starts,
                                             int* __restrict__ bsum)
{
    __shared__ int s[256];
    int b = blockIdx.x, tid = threadIdx.x;
    int v = counts[b * 256 + tid];
    s[tid] = v;
    __syncthreads();
    for (int o = 1; o < 256; o <<= 1) {
        int u = (tid >= o) ? s[tid - o] : 0;
        __syncthreads();
        s[tid] += u;
        __syncthreads();
    }
    starts[b * 256 + tid] = s[tid] - v;   // exclusive
    if (tid == 255) bsum[b] = s[255];
}

// K3: exclusive scan of the 256 block sums (single block)
__global__ __launch_bounds__(256) void scan2(int* __restrict__ bsum) {
    __shared__ int s[256];
    int tid = threadIdx.x;
    int v = bsum[tid];
    s[tid] = v;
    __syncthreads();
    for (int o = 1; o < 256; o <<= 1) {
        int u = (tid >= o) ? s[tid - o] : 0;
        __syncthreads();
        s[tid] += u;
        __syncthreads();
    }
    bsum[tid] = s[tid] - v;
}

// K4: add block offsets + sentinel
__global__ __launch_bounds__(256) void scan3(int* __restrict__ starts,
                                             const int* __restrict__ bsum)
{
    int b = blockIdx.x, tid = threadIdx.x;
    starts[b * 256 + tid] += bsum[b];
    if (b == 0 && tid == 0) starts[TOTP] = TOTP;   // sentinel
}

// K5: scatter points into cell-sorted pool
__global__ __launch_bounds__(256) void scatter(
    const float* __restrict__ c0, const float* __restrict__ c1,
    const int* __restrict__ cid, const int* __restrict__ starts,
    int* __restrict__ counts, float4* __restrict__ pts4, int* __restrict__ pidx)
{
    int t = blockIdx.x * 256 + threadIdx.x;
    int side = t >> 15, n = t & (N_PTS - 1);
    const float* c = side ? c1 : c0;
    float x = c[n * 3], y = c[n * 3 + 1], z = c[n * 3 + 2];
    float b2 = rn_add(rn_add(rn_mul(x, x), rn_mul(y, y)), rn_mul(z, z));
    int g = cid[t];
    int pos = starts[g] + (atomicSub(&counts[g], 1) - 1);
    pts4[pos] = make_float4(x, y, z, b2);
    pidx[pos] = n;
}

// K6: one WAVE per query; 2 independent waves per 128-thread block.
// Round 1: full r<=1 cube, 27 cells, 2 lanes/cell, 2-deep prefetch.
// Tail: Chebyshev-skip shells {2,3,5,8,13,21,31} (verified r15 enumeration).
// Value-only stop per radius; one exact lex butterfly at the end.
__global__ __launch_bounds__(128) void query2nn(
    const float* __restrict__ src, const float* __restrict__ tgt,
    const float* __restrict__ sc0, const float* __restrict__ sc1,
    const float4* __restrict__ pts4, const int* __restrict__ pidx,
    const int* __restrict__ starts, float* __restrict__ out)
{
    int lane = threadIdx.x & 63;
    int wv   = threadIdx.x >> 6;
    int qid  = blockIdx.x * 2 + wv;          // 0..16383
    int side = qid >> 13, q = qid & (M_Q - 1);
    const float* sc = side ? sc1 : sc0;

    float ax = sc[q * 3], ay = sc[q * 3 + 1], az = sc[q * 3 + 2];
    float a2 = rn_add(rn_add(rn_mul(ax, ax), rn_mul(ay, ay)), rn_mul(az, az));
    int cx = cellco(ax), cy = cellco(ay), cz = cellco(az);
    const int* st = starts + side * NC;

    float d1 = INF_F, d2 = INF_F;            // per-lane privates (disjoint pts)
    int   i1 = MAXI,  i2 = MAXI;

    // scan points [s0+sub, s1) stride `step`, 2-deep prefetch
    auto scan_pts = [&](int s0, int s1, int sub, int step) {
        int j = s0 + sub;
        if (j >= s1) return;
        float4 p = pts4[j];
        int    id = pidx[j];
        for (j += step; j < s1; j += step) {
            float4 pn = pts4[j];
            int    idn = pidx[j];
            float dot = __builtin_fmaf(az, p.z,
                         __builtin_fmaf(ay, p.y, rn_mul(ax, p.x)));
            float dd = __builtin_fmaf(-2.0f, dot, rn_add(a2, p.w));
            ins_lex(dd, id, d1, i1, d2, i2);
            p = pn; id = idn;
        }
        float dot = __builtin_fmaf(az, p.z,
                     __builtin_fmaf(ay, p.y, rn_mul(ax, p.x)));
        float dd = __builtin_fmaf(-2.0f, dot, rn_add(a2, p.w));
        ins_lex(dd, id, d1, i1, d2, i2);
    };

    // ---- Round 1: full r<=1 cube, 27 cells, 2 lanes per cell ----
    {
        int k = lane >> 1, sub = lane & 1;
        if (k < 27) {
            int dz = k / 9, rem = k - dz * 9;
            int dy = rem / 3, dx = rem - dy * 3;
            int xx = cx + dx - 1, yy = cy + dy - 1, zz = cz + dz - 1;
            if ((unsigned)xx < GS && (unsigned)yy < GS && (unsigned)zz < GS) {
                int c = (zz * GS + yy) * GS + xx;
                scan_pts(st[c], st[c + 1], sub, 2);
            }
        }
    }
    int rprev = 1;

    // stop test for r=1
    bool done;
    {
        float bnd = INF_F;
        int r = 1;
        if (cx - r > 0)      bnd = fminf(bnd, ax - (LOC + (cx - r) * CWID));
        if (cx + r < GS - 1) bnd = fminf(bnd, (LOC + (cx + r + 1) * CWID) - ax);
        if (cy - r > 0)      bnd = fminf(bnd, ay - (LOC + (cy - r) * CWID));
        if (cy + r < GS - 1) bnd = fminf(bnd, (LOC + (cy + r + 1) * CWID) - ay);
        if (cz - r > 0)      bnd = fminf(bnd, az - (LOC + (cz - r) * CWID));
        if (cz + r < GS - 1) bnd = fminf(bnd, (LOC + (cz + r + 1) * CWID) - az);
        if (bnd == INF_F) done = true;
        else {
            float p1 = d1, p2 = d2;
#pragma unroll
            for (int mk = 1; mk < 64; mk <<= 1) {
                float o1 = __shfl_xor(p1, mk);
                float o2 = __shfl_xor(p2, mk);
                vpair_merge(p1, p2, o1, o2);
            }
            done = (p2 < bnd * bnd - MARG);
        }
    }

    // ---- tail shells (sparse-region queries, ~3%) ----
    if (!done) {
        const int rs[7] = {2, 3, 5, 8, 13, 21, 31};
#pragma unroll 1
        for (int si = 0; si < 7; ++si) {
            int r = rs[si];
            int S = 2 * r + 1, S2 = S * S, tot = S * S2;
            for (int k = lane; k < tot; k += 64) {
                int dz = k / S2;
                int rem = k - dz * S2;
                int dy = rem / S;
                int dx = rem - dy * S;
                dx -= r; dy -= r; dz -= r;
                int adx = dx < 0 ? -dx : dx;
                int ady = dy < 0 ? -dy : dy;
                int adz = dz < 0 ? -dz : dz;
                int ch = max(adx, max(ady, adz));
                if (ch <= rprev) continue;                 // already scanned
                int xx = cx + dx, yy = cy + dy, zz = cz + dz;
                if ((unsigned)xx >= GS || (unsigned)yy >= GS ||
                    (unsigned)zz >= GS) continue;
                int c = (zz * GS + yy) * GS + xx;
                scan_pts(st[c], st[c + 1], 0, 1);
            }
            rprev = r;

            float bnd = INF_F;
            if (cx - r > 0)      bnd = fminf(bnd, ax - (LOC + (cx - r) * CWID));
            if (cx + r < GS - 1) bnd = fminf(bnd, (LOC + (cx + r + 1) * CWID) - ax);
            if (cy - r > 0)      bnd = fminf(bnd, ay - (LOC + (cy - r) * CWID));
            if (cy + r < GS - 1) bnd = fminf(bnd, (LOC + (cy + r + 1) * CWID) - ay);
            if (cz - r > 0)      bnd = fminf(bnd, az - (LOC + (cz - r) * CWID));
            if (cz + r < GS - 1) bnd = fminf(bnd, (LOC + (cz + r + 1) * CWID) - az);
            if (bnd == INF_F) break;                 // entire grid examined

            float p1 = d1, p2 = d2;
#pragma unroll
            for (int mk = 1; mk < 64; mk <<= 1) {
                float o1 = __shfl_xor(p1, mk);
                float o2 = __shfl_xor(p2, mk);
                vpair_merge(p1, p2, o1, o2);
            }
            if (p2 < bnd * bnd - MARG) break;        // rigorous exact stop
        }
    }

    // ---- one exact lex butterfly (privates pure; disjoint point sets) ----
    float t1 = d1, t2 = d2; int u1 = i1, u2 = i2;
#pragma unroll
    for (int mk = 1; mk < 64; mk <<= 1) {
        float o1 = __shfl_xor(t1, mk); int p1 = __shfl_xor(u1, mk);
        float o2 = __shfl_xor(t2, mk); int p2 = __shfl_xor(u2, mk);
        ins_lex(o1, p1, t1, u1, t2, u2);
        ins_lex2(o2, p2, t2, u2);
    }

    // fused gather: result uniform across the wave; 64 lanes x float4 = row
    const float* feats = side ? tgt : src;
    const float4* sp = (const float4*)(feats + (size_t)u2 * C_F);
    float4* dp = (float4*)(out + (size_t)qid * C_F);
    dp[lane] = sp[lane];
}

extern "C" void kernel_launch(void* const* d_in, const int* in_sizes, int n_in,
                              void* d_out, int out_size, void* d_ws, size_t ws_size,
                              hipStream_t stream) {
    const float* src  = (const float*)d_in[0];
    const float* tgt  = (const float*)d_in[1];
    const float* c0   = (const float*)d_in[2];  // src_coords   (N,3)
    const float* c1   = (const float*)d_in[3];  // tgt_coords   (N,3)
    const float* sh0  = (const float*)d_in[4];  // src_shortcut (M,3)
    const float* sh1  = (const float*)d_in[5];  // tgt_shortcut (M,3)
    float* out = (float*)d_out;

    char* w = (char*)d_ws;
    float4* pts4   = (float4*)(w);                       // 1,048,576
    int*    pidx   = (int*)(w + 1048576);                //   262,144
    int*    cid    = (int*)(w + 1310720);                //   262,144
    int*    counts = (int*)(w + 1572864);                //   262,144
    int*    starts = (int*)(w + 1835008);                //   262,148 (65537)
    int*    bsum   = (int*)(w + 2097280);                //     1,024

    hipMemsetAsync(counts, 0, (size_t)TOTP * sizeof(int), stream);

    hipLaunchKernelGGL(build_cells, dim3(TOTP / 256), dim3(256), 0, stream,
                       c0, c1, counts, cid);
    hipLaunchKernelGGL(scan1, dim3(TOTP / 256), dim3(256), 0, stream,
                       counts, starts, bsum);
    hipLaunchKernelGGL(scan2, dim3(1), dim3(256), 0, stream, bsum);
    hipLaunchKernelGGL(scan3, dim3(TOTP / 256), dim3(256), 0, stream,
                       starts, bsum);
    hipLaunchKernelGGL(scatter, dim3(TOTP / 256), dim3(256), 0, stream,
                       c0, c1, cid, starts, counts, pts4, pidx);
    hipLaunchKernelGGL(query2nn, dim3(TOTQ / 2), dim3(128), 0, stream,
                       src, tgt, sh0, sh1, pts4, pidx, starts, out);
}

// Round 19
// 80.881 us; speedup vs baseline: 2.8560x; 1.1058x over previous
//
#include <hip/hip_runtime.h>

#define N_PTS 32768
#define M_Q   8192
#define C_F   256
#define GS    32
#define NC    (GS * GS * GS)          // 32768 cells per side
#define TOTP  (2 * N_PTS)             // 65536 points
#define TOTQ  (2 * M_Q)               // 16384 queries
#define LOC   (-4.4f)
#define CWID  (8.8f / GS)             // 0.275
#define INVW  (GS / 8.8f)
#define MARG  2e-4f
#define INF_F __int_as_float(0x7f800000)
#define MAXI  0x7fffffff

__device__ __forceinline__ float rn_mul(float a, float b) { return __fmul_rn(a, b); }
__device__ __forceinline__ float rn_add(float a, float b) { return __fadd_rn(a, b); }

__device__ __forceinline__ int cellco(float v) {
    int c = (int)floorf((v - LOC) * INVW);
    return c < 0 ? 0 : (c > GS - 1 ? GS - 1 : c);
}

// exact lexicographic (d,i) insert into running top-2 pair
__device__ __forceinline__ void ins_lex(float d, int i, float& b1, int& j1,
                                        float& b2, int& j2) {
    bool lt1 = (d < b1) || (d == b1 && i < j1);
    bool lt2 = (d < b2) || (d == b2 && i < j2);
    b2 = lt1 ? b1 : (lt2 ? d : b2);
    j2 = lt1 ? j1 : (lt2 ? i : j2);
    b1 = lt1 ? d : b1;
    j1 = lt1 ? i : j1;
}
__device__ __forceinline__ void ins_lex2(float d, int i, float& b2, int& j2) {
    bool lt2 = (d < b2) || (d == b2 && i < j2);
    b2 = lt2 ? d : b2;
    j2 = lt2 ? i : j2;
}

// merge two sorted value-pairs -> two smallest values (multiset-exact)
__device__ __forceinline__ void vpair_merge(float& a1, float& a2, float b1, float b2) {
    float n1 = fminf(a1, b1);
    float n2 = fminf(fmaxf(a1, b1), fminf(a2, b2));
    a1 = n1; a2 = n2;
}

// K1: per-point cell id + histogram
__global__ __launch_bounds__(256) void build_cells(
    const float* __restrict__ c0, const float* __restrict__ c1,
    int* __restrict__ counts, int* __restrict__ cid)
{
    int t = blockIdx.x * 256 + threadIdx.x;     // 0..65535
    int side = t >> 15, n = t & (N_PTS - 1);
    const float* c = side ? c1 : c0;
    float x = c[n * 3], y = c[n * 3 + 1], z = c[n * 3 + 2];
    int g = side * NC + (cellco(z) * GS + cellco(y)) * GS + cellco(x);
    cid[t] = g;
    atomicAdd(&counts[g], 1);
}

// K2: per-256-block exclusive scan, emit block sums
__global__ __launch_bounds__(256) void scan1(const int* __restrict__ counts,
                                             int* __restrict__ starts,
                                             int* __restrict__ bsum)
{
    __shared__ int s[256];
    int b = blockIdx.x, tid = threadIdx.x;
    int v = counts[b * 256 + tid];
    s[tid] = v;
    __syncthreads();
    for (int o = 1; o < 256; o <<= 1) {
        int u = (tid >= o) ? s[tid - o] : 0;
        __syncthreads();
        s[tid] += u;
        __syncthreads();
    }
    starts[b * 256 + tid] = s[tid] - v;   // exclusive
    if (tid == 255) bsum[b] = s[255];
}

// K3: fused scan2+scan3 — each block locally scans the 256 block sums,
// takes its own exclusive prefix, adds to its starts slice.
__global__ __launch_bounds__(256) void scan23(int* __restrict__ starts,
                                              const int* __restrict__ bsum)
{
    __shared__ int s[256];
    int b = blockIdx.x, tid = threadIdx.x;
    int v = bsum[tid];
    s[tid] = v;
    __syncthreads();
    for (int o = 1; o < 256; o <<= 1) {
        int u = (tid >= o) ? s[tid - o] : 0;
        __syncthreads();
        s[tid] += u;
        __syncthreads();
    }
    int off = s[b] - bsum[b];             // exclusive prefix of bsum at b
    starts[b * 256 + tid] += off;
    if (b == 0 && tid == 0) starts[TOTP] = TOTP;   // sentinel
}

// K5: scatter points into cell-sorted pool
__global__ __launch_bounds__(256) void scatter(
    const float* __restrict__ c0, const float* __restrict__ c1,
    const int* __restrict__ cid, const int* __restrict__ starts,
    int* __restrict__ counts, float4* __restrict__ pts4, int* __restrict__ pidx)
{
    int t = blockIdx.x * 256 + threadIdx.x;
    int side = t >> 15, n = t & (N_PTS - 1);
    const float* c = side ? c1 : c0;
    float x = c[n * 3], y = c[n * 3 + 1], z = c[n * 3 + 2];
    float b2 = rn_add(rn_add(rn_mul(x, x), rn_mul(y, y)), rn_mul(z, z));
    int g = cid[t];
    int pos = starts[g] + (atomicSub(&counts[g], 1) - 1);
    pts4[pos] = make_float4(x, y, z, b2);
    pidx[pos] = n;
}

// K6: one WAVE per query; 2 independent waves per 128-thread block.
// Query-centered boxes [a±R]^3, R doubling: bnd >= R by construction, so the
// stop fires in one round for ~90% of queries. Nested boxes + prev-box skip
// => exactly-once insertion. Value-only stop; one exact lex butterfly.
__global__ __launch_bounds__(128) void query2nn(
    const float* __restrict__ src, const float* __restrict__ tgt,
    const float* __restrict__ sc0, const float* __restrict__ sc1,
    const float4* __restrict__ pts4, const int* __restrict__ pidx,
    const int* __restrict__ starts, float* __restrict__ out)
{
    int lane = threadIdx.x & 63;
    int wv   = threadIdx.x >> 6;
    int qid  = blockIdx.x * 2 + wv;          // 0..16383
    int side = qid >> 13, q = qid & (M_Q - 1);
    const float* sc = side ? sc1 : sc0;

    float ax = sc[q * 3], ay = sc[q * 3 + 1], az = sc[q * 3 + 2];
    float a2 = rn_add(rn_add(rn_mul(ax, ax), rn_mul(ay, ay)), rn_mul(az, az));
    const int* st = starts + side * NC;

    float d1 = INF_F, d2 = INF_F;            // per-lane privates (disjoint pts)
    int   i1 = MAXI,  i2 = MAXI;

    // scan points [s0+sub, s1) stride `step`, 2-deep prefetch
    auto scan_pts = [&](int s0, int s1, int sub, int step) {
        int j = s0 + sub;
        if (j >= s1) return;
        float4 p = pts4[j];
        int    id = pidx[j];
        for (j += step; j < s1; j += step) {
            float4 pn = pts4[j];
            int    idn = pidx[j];
            float dot = __builtin_fmaf(az, p.z,
                         __builtin_fmaf(ay, p.y, rn_mul(ax, p.x)));
            float dd = __builtin_fmaf(-2.0f, dot, rn_add(a2, p.w));
            ins_lex(dd, id, d1, i1, d2, i2);
            p = pn; id = idn;
        }
        float dot = __builtin_fmaf(az, p.z,
                     __builtin_fmaf(ay, p.y, rn_mul(ax, p.x)));
        float dd = __builtin_fmaf(-2.0f, dot, rn_add(a2, p.w));
        ins_lex(dd, id, d1, i1, d2, i2);
    };

    float R = 0.11f;
    int pxlo = 1, pxhi = 0, pylo = 1, pyhi = 0, pzlo = 1, pzhi = 0; // empty
#pragma unroll 1
    for (int round = 0; round < 10; ++round) {
        int xlo = cellco(ax - R), xhi = cellco(ax + R);
        int ylo = cellco(ay - R), yhi = cellco(ay + R);
        int zlo = cellco(az - R), zhi = cellco(az + R);
        int sx = xhi - xlo + 1, sy = yhi - ylo + 1, sz = zhi - zlo + 1;
        int C = sx * sy * sz;
        int SUB = 64 / C; if (SUB < 1) SUB = 1;   // lanes per cell
        int slots = C * SUB;
        int sxy = sx * sy;
        for (int k = lane; k < slots; k += 64) {
            int cell = k / SUB, sub = k - cell * SUB;
            int dz = cell / sxy; int rem = cell - dz * sxy;
            int dy = rem / sx;   int dx = rem - dy * sx;
            int xx = xlo + dx, yy = ylo + dy, zz = zlo + dz;
            if (xx >= pxlo && xx <= pxhi && yy >= pylo && yy <= pyhi &&
                zz >= pzlo && zz <= pzhi) continue;   // scanned in prev round
            int c = (zz * GS + yy) * GS + xx;
            scan_pts(st[c], st[c + 1], sub, SUB);
        }
        pxlo = xlo; pxhi = xhi; pylo = ylo; pyhi = yhi; pzlo = zlo; pzhi = zhi;

        // stop bound from the actual scanned-box faces (>= R on live axes)
        float bnd = INF_F;
        if (xlo > 0)      bnd = fminf(bnd, ax - (LOC + xlo * CWID));
        if (xhi < GS - 1) bnd = fminf(bnd, (LOC + (xhi + 1) * CWID) - ax);
        if (ylo > 0)      bnd = fminf(bnd, ay - (LOC + ylo * CWID));
        if (yhi < GS - 1) bnd = fminf(bnd, (LOC + (yhi + 1) * CWID) - ay);
        if (zlo > 0)      bnd = fminf(bnd, az - (LOC + zlo * CWID));
        if (zhi < GS - 1) bnd = fminf(bnd, (LOC + (zhi + 1) * CWID) - az);
        if (bnd == INF_F) break;                 // whole grid scanned

        // cheap exact 2nd-smallest VALUE across lanes for the stop test
        float p1 = d1, p2 = d2;
#pragma unroll
        for (int mk = 1; mk < 64; mk <<= 1) {
            float o1 = __shfl_xor(p1, mk);
            float o2 = __shfl_xor(p2, mk);
            vpair_merge(p1, p2, o1, o2);
        }
        if (p2 < bnd * bnd - MARG) break;        // rigorous exact stop
        R *= 2.0f;
    }

    // ---- one exact lex butterfly (privates pure; disjoint point sets) ----
    float t1 = d1, t2 = d2; int u1 = i1, u2 = i2;
#pragma unroll
    for (int mk = 1; mk < 64; mk <<= 1) {
        float o1 = __shfl_xor(t1, mk); int p1 = __shfl_xor(u1, mk);
        float o2 = __shfl_xor(t2, mk); int p2 = __shfl_xor(u2, mk);
        ins_lex(o1, p1, t1, u1, t2, u2);
        ins_lex2(o2, p2, t2, u2);
    }

    // fused gather: result uniform across the wave; 64 lanes x float4 = row
    const float* feats = side ? tgt : src;
    const float4* sp = (const float4*)(feats + (size_t)u2 * C_F);
    float4* dp = (float4*)(out + (size_t)qid * C_F);
    dp[lane] = sp[lane];
}

extern "C" void kernel_launch(void* const* d_in, const int* in_sizes, int n_in,
                              void* d_out, int out_size, void* d_ws, size_t ws_size,
                              hipStream_t stream) {
    const float* src  = (const float*)d_in[0];
    const float* tgt  = (const float*)d_in[1];
    const float* c0   = (const float*)d_in[2];  // src_coords   (N,3)
    const float* c1   = (const float*)d_in[3];  // tgt_coords   (N,3)
    const float* sh0  = (const float*)d_in[4];  // src_shortcut (M,3)
    const float* sh1  = (const float*)d_in[5];  // tgt_shortcut (M,3)
    float* out = (float*)d_out;

    char* w = (char*)d_ws;
    float4* pts4   = (float4*)(w);                       // 1,048,576
    int*    pidx   = (int*)(w + 1048576);                //   262,144
    int*    cid    = (int*)(w + 1310720);                //   262,144
    int*    counts = (int*)(w + 1572864);                //   262,144
    int*    starts = (int*)(w + 1835008);                //   262,148 (65537)
    int*    bsum   = (int*)(w + 2097280);                //     1,024

    hipMemsetAsync(counts, 0, (size_t)TOTP * sizeof(int), stream);

    hipLaunchKernelGGL(build_cells, dim3(TOTP / 256), dim3(256), 0, stream,
                       c0, c1, counts, cid);
    hipLaunchKernelGGL(scan1, dim3(TOTP / 256), dim3(256), 0, stream,
                       counts, starts, bsum);
    hipLaunchKernelGGL(scan23, dim3(TOTP / 256), dim3(256), 0, stream,
                       starts, bsum);
    hipLaunchKernelGGL(scatter, dim3(TOTP / 256), dim3(256), 0, stream,
                       c0, c1, cid, starts, counts, pts4, pidx);
    hipLaunchKernelGGL(query2nn, dim3(TOTQ / 2), dim3(128), 0, stream,
                       src, tgt, sh0, sh1, pts4, pidx, starts, out);
}

// Round 20
// 54.307 us; speedup vs baseline: 4.2534x; 1.4893x over previous
//
#include <hip/hip_runtime.h>

#define N_PTS 32768
#define M_Q   8192
#define C_F   256
#define GS    32
#define NC    (GS * GS * GS)          // 32768 cells per side
#define TOTP  (2 * N_PTS)             // 65536 points
#define TOTQ  (2 * M_Q)               // 16384 queries
#define LOC   (-4.4f)
#define CWID  (8.8f / GS)             // 0.275
#define INVW  (GS / 8.8f)
#define MARG  2e-4f
#define INF_F __int_as_float(0x7f800000)
#define MAXI  0x7fffffff

__device__ __forceinline__ float rn_mul(float a, float b) { return __fmul_rn(a, b); }
__device__ __forceinline__ float rn_add(float a, float b) { return __fadd_rn(a, b); }

__device__ __forceinline__ int cellco(float v) {
    int c = (int)floorf((v - LOC) * INVW);
    return c < 0 ? 0 : (c > GS - 1 ? GS - 1 : c);
}

// exact lexicographic (d,i) insert into running top-2 pair
__device__ __forceinline__ void ins_lex(float d, int i, float& b1, int& j1,
                                        float& b2, int& j2) {
    bool lt1 = (d < b1) || (d == b1 && i < j1);
    bool lt2 = (d < b2) || (d == b2 && i < j2);
    b2 = lt1 ? b1 : (lt2 ? d : b2);
    j2 = lt1 ? j1 : (lt2 ? i : j2);
    b1 = lt1 ? d : b1;
    j1 = lt1 ? i : j1;
}
__device__ __forceinline__ void ins_lex2(float d, int i, float& b2, int& j2) {
    bool lt2 = (d < b2) || (d == b2 && i < j2);
    b2 = lt2 ? d : b2;
    j2 = lt2 ? i : j2;
}

// merge two sorted value-pairs -> two smallest values (multiset-exact)
__device__ __forceinline__ void vpair_merge(float& a1, float& a2, float b1, float b2) {
    float n1 = fminf(a1, b1);
    float n2 = fminf(fmaxf(a1, b1), fminf(a2, b2));
    a1 = n1; a2 = n2;
}

// K1: per-point cell id + histogram
__global__ __launch_bounds__(256) void build_cells(
    const float* __restrict__ c0, const float* __restrict__ c1,
    int* __restrict__ counts, int* __restrict__ cid)
{
    int t = blockIdx.x * 256 + threadIdx.x;     // 0..65535
    int side = t >> 15, n = t & (N_PTS - 1);
    const float* c = side ? c1 : c0;
    float x = c[n * 3], y = c[n * 3 + 1], z = c[n * 3 + 2];
    int g = side * NC + (cellco(z) * GS + cellco(y)) * GS + cellco(x);
    cid[t] = g;
    atomicAdd(&counts[g], 1);
}

// K2: per-256-block exclusive scan, emit block sums
__global__ __launch_bounds__(256) void scan1(const int* __restrict__ counts,
                                             int* __restrict__ starts,
                                             int* __restrict__ bsum)
{
    __shared__ int s[256];
    int b = blockIdx.x, tid = threadIdx.x;
    int v = counts[b * 256 + tid];
    s[tid] = v;
    __syncthreads();
    for (int o = 1; o < 256; o <<= 1) {
        int u = (tid >= o) ? s[tid - o] : 0;
        __syncthreads();
        s[tid] += u;
        __syncthreads();
    }
    starts[b * 256 + tid] = s[tid] - v;   // exclusive
    if (tid == 255) bsum[b] = s[255];
}

// K3: fused scan2+scan3 — each block locally scans the 256 block sums,
// takes its own exclusive prefix, adds to its starts slice.
__global__ __launch_bounds__(256) void scan23(int* __restrict__ starts,
                                              const int* __restrict__ bsum)
{
    __shared__ int s[256];
    int b = blockIdx.x, tid = threadIdx.x;
    int v = bsum[tid];
    s[tid] = v;
    __syncthreads();
    for (int o = 1; o < 256; o <<= 1) {
        int u = (tid >= o) ? s[tid - o] : 0;
        __syncthreads();
        s[tid] += u;
        __syncthreads();
    }
    int off = s[b] - bsum[b];             // exclusive prefix of bsum at b
    starts[b * 256 + tid] += off;
    if (b == 0 && tid == 0) starts[TOTP] = TOTP;   // sentinel
}

// K5: scatter points into cell-sorted pool
__global__ __launch_bounds__(256) void scatter(
    const float* __restrict__ c0, const float* __restrict__ c1,
    const int* __restrict__ cid, const int* __restrict__ starts,
    int* __restrict__ counts, float4* __restrict__ pts4, int* __restrict__ pidx)
{
    int t = blockIdx.x * 256 + threadIdx.x;
    int side = t >> 15, n = t & (N_PTS - 1);
    const float* c = side ? c1 : c0;
    float x = c[n * 3], y = c[n * 3 + 1], z = c[n * 3 + 2];
    float b2 = rn_add(rn_add(rn_mul(x, x), rn_mul(y, y)), rn_mul(z, z));
    int g = cid[t];
    int pos = starts[g] + (atomicSub(&counts[g], 1) - 1);
    pts4[pos] = make_float4(x, y, z, b2);
    pidx[pos] = n;
}

// K6: one WAVE per query; 2 independent waves per 128-thread block.
// Query-centered boxes with ROW-parallel scanning: each (z,y) cell-row of the
// box is x-contiguous in the sorted array -> one starts-pair per row; lanes
// own (row, sub) slots. Density-adaptive R0 from the query cell's count.
// Nested boxes + row x-subrange skip => exactly-once. Value-only stop;
// one exact lex butterfly at the end.
__global__ __launch_bounds__(128) void query2nn(
    const float* __restrict__ src, const float* __restrict__ tgt,
    const float* __restrict__ sc0, const float* __restrict__ sc1,
    const float4* __restrict__ pts4, const int* __restrict__ pidx,
    const int* __restrict__ starts, float* __restrict__ out)
{
    int lane = threadIdx.x & 63;
    int wv   = threadIdx.x >> 6;
    int qid  = blockIdx.x * 2 + wv;          // 0..16383
    int side = qid >> 13, q = qid & (M_Q - 1);
    const float* sc = side ? sc1 : sc0;

    float ax = sc[q * 3], ay = sc[q * 3 + 1], az = sc[q * 3 + 2];
    float a2 = rn_add(rn_add(rn_mul(ax, ax), rn_mul(ay, ay)), rn_mul(az, az));
    const int* st = starts + side * NC;

    float d1 = INF_F, d2 = INF_F;            // per-lane privates (disjoint pts)
    int   i1 = MAXI,  i2 = MAXI;

    // scan points [s0+sub, s1) stride `step`, 2-deep prefetch
    auto scan_range = [&](int s0, int s1, int sub, int step) {
        int j = s0 + sub;
        if (j >= s1) return;
        float4 p = pts4[j];
        int    id = pidx[j];
        for (j += step; j < s1; j += step) {
            float4 pn = pts4[j];
            int    idn = pidx[j];
            float dot = __builtin_fmaf(az, p.z,
                         __builtin_fmaf(ay, p.y, rn_mul(ax, p.x)));
            float dd = __builtin_fmaf(-2.0f, dot, rn_add(a2, p.w));
            ins_lex(dd, id, d1, i1, d2, i2);
            p = pn; id = idn;
        }
        float dot = __builtin_fmaf(az, p.z,
                     __builtin_fmaf(ay, p.y, rn_mul(ax, p.x)));
        float dd = __builtin_fmaf(-2.0f, dot, rn_add(a2, p.w));
        ins_lex(dd, id, d1, i1, d2, i2);
    };

    // density-adaptive initial radius from the query cell's own count
    int cx = cellco(ax), cy = cellco(ay), cz = cellco(az);
    int cc = (cz * GS + cy) * GS + cx;
    int n0 = st[cc + 1] - st[cc];            // wave-uniform
    float R = (n0 >= 6) ? 0.12f : ((n0 >= 2) ? 0.19f : 0.30f);

    int pxlo = 0, pxhi = -1, pylo = 0, pyhi = -1, pzlo = 0, pzhi = -1; // empty
#pragma unroll 1
    for (int round = 0; round < 12; ++round) {
        int xlo = cellco(ax - R), xhi = cellco(ax + R);
        int ylo = cellco(ay - R), yhi = cellco(ay + R);
        int zlo = cellco(az - R), zhi = cellco(az + R);
        int sy = yhi - ylo + 1, sz = zhi - zlo + 1;
        int rows = sy * sz;
        int SUB = 64 / rows; if (SUB < 1) SUB = 1;   // lanes per row
        int slots = rows * SUB;
        for (int k = lane; k < slots; k += 64) {
            int row = k / SUB, sub = k - row * SUB;
            int dz = row / sy, dy = row - dz * sy;
            int zz = zlo + dz, yy = ylo + dy;
            int rowbase = (zz * GS + yy) * GS;
            bool inPrev = (zz >= pzlo && zz <= pzhi && yy >= pylo && yy <= pyhi);
            if (inPrev) {
                // only the two x-subranges outside the previous box are new
                scan_range(st[rowbase + xlo], st[rowbase + pxlo], sub, SUB);
                scan_range(st[rowbase + pxhi + 1], st[rowbase + xhi + 1], sub, SUB);
            } else {
                scan_range(st[rowbase + xlo], st[rowbase + xhi + 1], sub, SUB);
            }
        }
        pxlo = xlo; pxhi = xhi; pylo = ylo; pyhi = yhi; pzlo = zlo; pzhi = zhi;

        // stop bound from the scanned-box faces (>= R on non-edge axes)
        float bnd = INF_F;
        if (xlo > 0)      bnd = fminf(bnd, ax - (LOC + xlo * CWID));
        if (xhi < GS - 1) bnd = fminf(bnd, (LOC + (xhi + 1) * CWID) - ax);
        if (ylo > 0)      bnd = fminf(bnd, ay - (LOC + ylo * CWID));
        if (yhi < GS - 1) bnd = fminf(bnd, (LOC + (yhi + 1) * CWID) - ay);
        if (zlo > 0)      bnd = fminf(bnd, az - (LOC + zlo * CWID));
        if (zhi < GS - 1) bnd = fminf(bnd, (LOC + (zhi + 1) * CWID) - az);
        if (bnd == INF_F) break;                 // whole grid scanned

        // cheap exact 2nd-smallest VALUE across lanes for the stop test
        float p1 = d1, p2 = d2;
#pragma unroll
        for (int mk = 1; mk < 64; mk <<= 1) {
            float o1 = __shfl_xor(p1, mk);
            float o2 = __shfl_xor(p2, mk);
            vpair_merge(p1, p2, o1, o2);
        }
        if (p2 < bnd * bnd - MARG) break;        // rigorous exact stop
        R *= 2.0f;
    }

    // ---- one exact lex butterfly (privates pure; disjoint point sets) ----
    float t1 = d1, t2 = d2; int u1 = i1, u2 = i2;
#pragma unroll
    for (int mk = 1; mk < 64; mk <<= 1) {
        float o1 = __shfl_xor(t1, mk); int p1 = __shfl_xor(u1, mk);
        float o2 = __shfl_xor(t2, mk); int p2 = __shfl_xor(u2, mk);
        ins_lex(o1, p1, t1, u1, t2, u2);
        ins_lex2(o2, p2, t2, u2);
    }

    // fused gather: result uniform across the wave; 64 lanes x float4 = row
    const float* feats = side ? tgt : src;
    const float4* sp = (const float4*)(feats + (size_t)u2 * C_F);
    float4* dp = (float4*)(out + (size_t)qid * C_F);
    dp[lane] = sp[lane];
}

extern "C" void kernel_launch(void* const* d_in, const int* in_sizes, int n_in,
                              void* d_out, int out_size, void* d_ws, size_t ws_size,
                              hipStream_t stream) {
    const float* src  = (const float*)d_in[0];
    const float* tgt  = (const float*)d_in[1];
    const float* c0   = (const float*)d_in[2];  // src_coords   (N,3)
    const float* c1   = (const float*)d_in[3];  // tgt_coords   (N,3)
    const float* sh0  = (const float*)d_in[4];  // src_shortcut (M,3)
    const float* sh1  = (const float*)d_in[5];  // tgt_shortcut (M,3)
    float* out = (float*)d_out;

    char* w = (char*)d_ws;
    float4* pts4   = (float4*)(w);                       // 1,048,576
    int*    pidx   = (int*)(w + 1048576);                //   262,144
    int*    cid    = (int*)(w + 1310720);                //   262,144
    int*    counts = (int*)(w + 1572864);                //   262,144
    int*    starts = (int*)(w + 1835008);                //   262,148 (65537)
    int*    bsum   = (int*)(w + 2097280);                //     1,024

    hipMemsetAsync(counts, 0, (size_t)TOTP * sizeof(int), stream);

    hipLaunchKernelGGL(build_cells, dim3(TOTP / 256), dim3(256), 0, stream,
                       c0, c1, counts, cid);
    hipLaunchKernelGGL(scan1, dim3(TOTP / 256), dim3(256), 0, stream,
                       counts, starts, bsum);
    hipLaunchKernelGGL(scan23, dim3(TOTP / 256), dim3(256), 0, stream,
                       starts, bsum);
    hipLaunchKernelGGL(scatter, dim3(TOTP / 256), dim3(256), 0, stream,
                       c0, c1, cid, starts, counts, pts4, pidx);
    hipLaunchKernelGGL(query2nn, dim3(TOTQ / 2), dim3(128), 0, stream,
                       src, tgt, sh0, sh1, pts4, pidx, starts, out);
}